// Round 1
// 1243.869 us; speedup vs baseline: 1.1142x; 1.1142x over previous
//
#include <hip/hip_runtime.h>
#include <hip/hip_bf16.h>

using u16 = unsigned short;
using short8 = __attribute__((ext_vector_type(8))) short;
using floatx4 = __attribute__((ext_vector_type(4))) float;

#define DEVI static __device__ __forceinline__

constexpr int cB = 4, cN = 4096, cD = 768, cE = 4, cS = 1024, cH = 3072;
constexpr int cES = cE * cS; // 4096
constexpr int cHC = cH / 2;  // 1536 H-chunk

DEVI u16 f2bf(float f) {
  union { float f; unsigned u; } v; v.f = f;
  unsigned r = v.u + 0x7fffu + ((v.u >> 16) & 1u); // RNE
  return (u16)(r >> 16);
}
DEVI float bf2f(u16 b) {
  union { unsigned u; float f; } v; v.u = ((unsigned)b) << 16;
  return v.f;
}
DEVI float gelu_tanh(float x) {
  // jax.nn.gelu default: approximate=True (tanh form)
  float z = 1.5957691216057308f * (x + 0.044715f * x * x * x);
  z = fminf(fmaxf(z, -30.f), 30.f);
  float e = __expf(z);
  float t = (e - 1.f) / (e + 1.f);
  return 0.5f * x * (1.f + t);
}

// async global->LDS, 16B per lane; lds dest = wave-uniform base + lane*16
DEVI void glds16(const u16* g, u16* l) {
  __builtin_amdgcn_global_load_lds(
      (const __attribute__((address_space(1))) void*)g,
      (__attribute__((address_space(3))) void*)l, 16, 0, 0);
}

// ---------------- zero fp32 buffer ----------------
__global__ __launch_bounds__(256) void zero_kernel(float* __restrict__ p, int n) {
  int i = blockIdx.x * 256 + threadIdx.x;
  if (i < n) p[i] = 0.f;
}

// ---------------- elementwise convert f32 -> bf16 ----------------
__global__ __launch_bounds__(256) void convert_kernel(const float* __restrict__ in,
                                                      u16* __restrict__ out, long n) {
  long stride = (long)gridDim.x * 256 * 4;
  for (long idx = ((long)blockIdx.x * 256 + threadIdx.x) * 4; idx < n; idx += stride) {
    float4 v = *(const float4*)(in + idx);
    ushort4 o;
    o.x = f2bf(v.x); o.y = f2bf(v.y); o.z = f2bf(v.z); o.w = f2bf(v.w);
    *(ushort4*)(out + idx) = o;
  }
}

// ---------------- batched transpose [R][C] -> [C][R], output bf16 ----------------
DEVI u16 to_bf(float f) { return f2bf(f); }
DEVI u16 to_bf(u16 u) { return u; }

template <typename Tin>
__global__ __launch_bounds__(256) void transpose_bf16_kernel(const Tin* __restrict__ in,
                                                             u16* __restrict__ out,
                                                             int R, int C,
                                                             long strideIn, long strideOut) {
  __shared__ u16 tile[64][65];
  const Tin* inb = in + (long)blockIdx.z * strideIn;
  u16* outb = out + (long)blockIdx.z * strideOut;
  const int r0 = blockIdx.y * 64, c0 = blockIdx.x * 64;
  const int tid = threadIdx.x;
#pragma unroll
  for (int i = 0; i < 16; i++) {
    int idx = i * 256 + tid;
    int r = idx >> 6, c = idx & 63;
    tile[r][c] = to_bf(inb[(long)(r0 + r) * C + (c0 + c)]);
  }
  __syncthreads();
#pragma unroll
  for (int i = 0; i < 16; i++) {
    int idx = i * 256 + tid;
    int r = idx >> 6, c = idx & 63;
    outb[(long)(c0 + r) * R + (r0 + c)] = tile[c][r];
  }
}

// ---------------- Z2: row sums (one block per row) ----------------
__global__ __launch_bounds__(256) void rowsum_kernel(const u16* __restrict__ P,
                                                     float* __restrict__ Z, int cols) {
  long base = (long)blockIdx.x * cols;
  int tid = threadIdx.x;
  float s = 0.f;
  for (int c = tid * 4; c < cols; c += 256 * 4) {
    ushort4 v = *(const ushort4*)(P + base + c);
    s += bf2f(v.x) + bf2f(v.y) + bf2f(v.z) + bf2f(v.w);
  }
  for (int o = 32; o > 0; o >>= 1) s += __shfl_down(s, o, 64);
  __shared__ float ws4[4];
  if ((tid & 63) == 0) ws4[tid >> 6] = s;
  __syncthreads();
  if (tid == 0) Z[blockIdx.x] = ws4[0] + ws4[1] + ws4[2] + ws4[3];
}

// ---------------- Z1: column sums, chunked + atomic (Z pre-zeroed) ----------------
__global__ __launch_bounds__(256) void colsum_kernel(const u16* __restrict__ P,
                                                     float* __restrict__ Z, int cols) {
  int col = blockIdx.x * 256 + threadIdx.x;
  int r0 = blockIdx.y * 256;
  float s = 0.f;
  for (int r = r0; r < r0 + 256; r++) s += bf2f(P[(long)r * cols + col]);
  atomicAdd(Z + col, s);
}

// ---------------- NT GEMM: C[m][n] = sum_k A[m][k] * B[n][k], bf16 MFMA ----------------
// Engine v2: quad-buffered LDS (4 x 16KB), prefetch distance 3, counted vmcnt(12),
// raw s_barrier (no vmcnt(0) drain in main loop), T2 XOR k-slot swizzle
// (conflict-free ds_read_b128 on 64B rows), T1 XCD block swizzle, T5 setprio.
// EPI: 0 exp->bf16
//      1 v/rowVec->bf16
//      2 gelu(v+colVec)->bf16
//      3 v+colVec->bf16
//      4 v/rowVec->f32
//      5 v+prevC->bf16 (read-accumulate)
template <int EPI>
__global__ __launch_bounds__(256, 2) void gemm_nt(const u16* __restrict__ A,
                                                  const u16* __restrict__ Bm,
                                                  void* __restrict__ Cout,
                                                  int M, int Nn, int K,
                                                  long ldA, long ldB, long ldC,
                                                  long strideA, long strideB, int modB,
                                                  long strideC,
                                                  const float* __restrict__ epiVec,
                                                  long epiStride, int epiMod) {
  __shared__ u16 lds[4 * 8192]; // 4 bufs x (A 4096 elems + B 4096 elems) = 64KB

  // ---- T1: bijective XCD swizzle on flattened (x,y); all grids here have nwg%8==0
  const int gx = gridDim.x;
  const int nwg = gx * gridDim.y;
  int flat = blockIdx.y * gx + blockIdx.x;
  if ((nwg & 7) == 0) flat = (flat & 7) * (nwg >> 3) + (flat >> 3);
  const int bxs = flat % gx, bys = flat / gx;

  const int bz = blockIdx.z;
  const u16* Ab = A + (long)bz * strideA;
  const u16* Bb = Bm + (long)(bz % modB) * strideB;
  const float* ev = epiVec + (long)(bz % epiMod) * epiStride;
  const int tileM = bys * 128, tileN = bxs * 128;
  const int tid = threadIdx.x;
  const int wave = tid >> 6, lane = tid & 63;
  const int quad = lane >> 4, l16 = lane & 15;
  const int wm = (wave >> 1) * 64, wn = (wave & 1) * 64;

  // ---- staging geometry: tile = 128 rows x 32 k; wave w covers elems
  // [(w*2+c)*512, +512) for chunk c; lane l -> elem base + l*8. LDS fill is linear
  // (glds lane mapping), so the T2 swizzle is applied on the GLOBAL k-slot:
  // physical slot sp holds logical slot sp ^ ((row>>1)&3).
  const int swzk = (((lane & 3) ^ ((lane >> 3) & 3)) << 3); // logical k for this lane's slot
  const int r0 = wave * 32 + (lane >> 2);                   // chunk0 row; chunk1 = +16
  const u16* aG0 = Ab + (long)(tileM + r0) * ldA + swzk;
  const u16* aG1 = Ab + (long)(tileM + r0 + 16) * ldA + swzk;
  const u16* bG0 = Bb + (long)(tileN + r0) * ldB + swzk;
  const u16* bG1 = Bb + (long)(tileN + r0 + 16) * ldB + swzk;
  const int ldsW = wave * 1024; // wave-uniform LDS elem base

  const int NT = K >> 5;

  auto STAGE = [&](int tt) {
    u16* l = &lds[(tt & 3) * 8192];
    const long ko = (long)tt << 5;
    glds16(aG0 + ko, l + ldsW);
    glds16(aG1 + ko, l + ldsW + 512);
    glds16(bG0 + ko, l + 4096 + ldsW);
    glds16(bG1 + ko, l + 4096 + ldsW + 512);
  };

  floatx4 acc[4][4] = {};
  // read side: logical k-slot = quad lives at physical slot quad ^ ((row>>1)&3);
  // (row>>1)&3 == (l16>>1)&3 for all frag rows (wm, i*16 are multiples of 16)
  const int sread = ((quad ^ ((l16 >> 1) & 3)) << 3);

  STAGE(0);
  if (NT > 1) STAGE(1);
  if (NT > 2) STAGE(2);

  for (int t = 0; t < NT; t++) {
    // barrier A: all waves' ds_reads of iter t-1 retired (consumed by their MFMAs)
    // before we clobber buf (t+3)&3 == (t-1)&3
    asm volatile("s_barrier" ::: "memory");
    if (t + 3 < NT) STAGE(t + 3);
    // counted vmcnt: allow the 3 prefetched tiles (12 loads) to stay in flight;
    // guarantees tile t's 4 loads (per wave) have landed. Peeled tail counts.
    const int ahead = NT - 1 - t;
    if (ahead >= 3)      asm volatile("s_waitcnt vmcnt(12)" ::: "memory");
    else if (ahead == 2) asm volatile("s_waitcnt vmcnt(8)" ::: "memory");
    else if (ahead == 1) asm volatile("s_waitcnt vmcnt(4)" ::: "memory");
    else                 asm volatile("s_waitcnt vmcnt(0)" ::: "memory");
    // barrier B: every wave passed its own vmcnt -> tile t fully resident in LDS
    asm volatile("s_barrier" ::: "memory");

    const u16* As = &lds[(t & 3) * 8192];
    const u16* Bs = As + 4096;
    short8 af[4], bq[4];
#pragma unroll
    for (int i = 0; i < 4; i++)
      af[i] = *(const short8*)&As[(wm + i * 16 + l16) * 32 + sread];
#pragma unroll
    for (int j = 0; j < 4; j++)
      bq[j] = *(const short8*)&Bs[(wn + j * 16 + l16) * 32 + sread];
    __builtin_amdgcn_s_setprio(1);
#pragma unroll
    for (int i = 0; i < 4; i++)
#pragma unroll
      for (int j = 0; j < 4; j++)
        acc[i][j] = __builtin_amdgcn_mfma_f32_16x16x32_bf16(af[i], bq[j], acc[i][j], 0, 0, 0);
    __builtin_amdgcn_s_setprio(0);
  }

  // C/D layout: col = lane&15, row = quad*4 + r  (m89/m91-verified)
  const long cBase = (long)bz * strideC;
#pragma unroll
  for (int i = 0; i < 4; i++) {
#pragma unroll
    for (int r = 0; r < 4; r++) {
      const int row = tileM + wm + i * 16 + quad * 4 + r;
      float rscale = 1.f;
      if (EPI == 1 || EPI == 4) rscale = 1.f / ev[row];
#pragma unroll
      for (int j = 0; j < 4; j++) {
        const int col = tileN + wn + j * 16 + l16;
        float v = acc[i][j][r];
        const long cIdx = cBase + (long)row * ldC + col;
        if (EPI == 0) v = __expf(v);
        if (EPI == 1 || EPI == 4) v *= rscale;
        if (EPI == 2) v = gelu_tanh(v + ev[col]);
        if (EPI == 3) v = v + ev[col];
        if (EPI == 5) v = v + bf2f(((u16*)Cout)[cIdx]);
        if (EPI == 4)
          ((float*)Cout)[cIdx] = v;
        else
          ((u16*)Cout)[cIdx] = f2bf(v);
      }
    }
  }
}

extern "C" void kernel_launch(void* const* d_in, const int* in_sizes, int n_in,
                              void* d_out, int out_size, void* d_ws, size_t ws_size,
                              hipStream_t stream) {
  const float* x   = (const float*)d_in[0]; // [B,N,D]
  const float* phi = (const float*)d_in[1]; // [E,S,D]
  const float* w1  = (const float*)d_in[2]; // [E,D,H]
  const float* b1  = (const float*)d_in[3]; // [E,H]
  const float* w2  = (const float*)d_in[4]; // [E,H,D]
  const float* b2  = (const float*)d_in[5]; // [E,D]
  (void)in_sizes; (void)n_in; (void)out_size; (void)ws_size;
  float* out_f = (float*)d_out;

  char* ws = (char*)d_ws;
  size_t off = 0;
  auto carve = [&](size_t bytes) -> char* {
    char* p = ws + off;
    off += (bytes + 255) & ~(size_t)255;
    return p;
  };

  // ---- workspace (~187 MB total) ----
  const size_t SZ_P = (size_t)cN * cES * 2; // 33.55 MB
  char* R1 = carve(2 * SZ_P);               // 67.1 MB multi-use region
  u16* Pb  = (u16*)R1;                      // phase A: P_b [N][ES]
  u16* Ptb = (u16*)(R1 + SZ_P);             // phase A: Pt_b [ES][N]
  u16* Hc  = (u16*)R1;                      // phase B: H chunk [16][S][1536] (50.3 MB)
  u16* P2  = (u16*)R1;                      // phase C: P pair [2][N][ES] (67.1 MB)
  u16* Xbf = (u16*)carve((size_t)cB * cN * cD * 2);   // persistent (phase A + C)
  char* R3 = carve((size_t)cB * cD * cN * 2);
  u16* Xt = (u16*)R3;                       // phase A: [B][D][N]
  u16* Yv = (u16*)R3;                       // phase B/C: [B][ES][D]
  char* R4 = carve((size_t)cB * cES * cD * 2);
  u16* Slots = (u16*)R4;                    // phase A/B: [B][ES][D]
  u16* Yt    = (u16*)R4;                    // phase C: [B][D][ES] (same 25.2 MB)
  u16* Phibf = (u16*)carve((size_t)cES * cD * 2);     // persistent (recompute)
  u16* W1t = (u16*)carve((size_t)cE * cH * cD * 2);   // [e][h][d]
  u16* W2t = (u16*)carve((size_t)cE * cD * cH * 2);   // [e][d][h]
  float* Z1 = (float*)carve((size_t)cB * cES * 4);
  float* Z2 = (float*)carve((size_t)cB * cN * 4);

  // ---- phase 0: casts / weight transposes ----
  convert_kernel<<<2048, 256, 0, stream>>>(x, Xbf, (long)cB * cN * cD);
  convert_kernel<<<1024, 256, 0, stream>>>(phi, Phibf, (long)cES * cD);
  transpose_bf16_kernel<float><<<dim3(cH / 64, cD / 64, cE), 256, 0, stream>>>(
      w1, W1t, cD, cH, (long)cD * cH, (long)cH * cD);
  transpose_bf16_kernel<float><<<dim3(cD / 64, cH / 64, cE), 256, 0, stream>>>(
      w2, W2t, cH, cD, (long)cH * cD, (long)cD * cH);
  transpose_bf16_kernel<float><<<dim3(cD / 64, cN / 64, cB), 256, 0, stream>>>(
      x, Xt, cN, cD, (long)cN * cD, (long)cD * cN);
  zero_kernel<<<(cB * cES) / 256, 256, 0, stream>>>(Z1, cB * cES);

  // ---- phase A: per batch, P_b -> Z1,Z2 -> Pt_b -> Slots_b ----
  for (int b = 0; b < cB; b++) {
    const u16* Xb = Xbf + (long)b * cN * cD;
    // P_b[n][es] = exp(X_b . Phi^T)
    gemm_nt<0><<<dim3(cES / 128, cN / 128, 1), 256, 0, stream>>>(
        Xb, Phibf, Pb, cN, cES, cD, cD, cD, cES,
        0L, 0L, 1, 0L, Z1, 0, 1);
    colsum_kernel<<<dim3(cES / 256, cN / 256, 1), 256, 0, stream>>>(
        Pb, Z1 + (long)b * cES, cES);
    rowsum_kernel<<<cN, 256, 0, stream>>>(Pb, Z2 + (long)b * cN, cES);
    transpose_bf16_kernel<u16><<<dim3(cES / 64, cN / 64, 1), 256, 0, stream>>>(
        Pb, Ptb, cN, cES, 0L, 0L);
    // Slots_b[es][d] = (Pt_b . Xt_b^T) / Z1_b
    gemm_nt<1><<<dim3(cD / 128, cES / 128, 1), 256, 0, stream>>>(
        Ptb, Xt + (long)b * cD * cN, Slots + (long)b * cES * cD,
        cES, cD, cN, cN, cN, cD,
        0L, 0L, 1, 0L, Z1 + (long)b * cES, 0, 1);
  }

  // ---- phase B: MLP in 2 H-chunks (bz = b*4+e) ----
  for (int hc = 0; hc < 2; hc++) {
    const int h0 = hc * cHC;
    // Hc[bz][s][hchunk] = gelu(Slots . W1t[:, h0:h0+HC]^T + b1[h0:])
    gemm_nt<2><<<dim3(cHC / 128, cS / 128, cB * cE), 256, 0, stream>>>(
        Slots, W1t + (long)h0 * cD, Hc, cS, cHC, cD, cD, cD, cHC,
        (long)cS * cD, (long)cH * cD, cE, (long)cS * cHC, b1 + h0, cH, cE);
    // Yv[bz][s][d] (+)= Hc . W2t[:, h0:h0+HC]^T (+ b2 on first chunk)
    if (hc == 0)
      gemm_nt<3><<<dim3(cD / 128, cS / 128, cB * cE), 256, 0, stream>>>(
          Hc, W2t + h0, Yv, cS, cD, cHC, cHC, cH, cD,
          (long)cS * cHC, (long)cD * cH, cE, (long)cS * cD, b2, cD, cE);
    else
      gemm_nt<5><<<dim3(cD / 128, cS / 128, cB * cE), 256, 0, stream>>>(
          Hc, W2t + h0, Yv, cS, cD, cHC, cHC, cH, cD,
          (long)cS * cHC, (long)cD * cH, cE, (long)cS * cD, b2, cD, cE);
  }

  // ---- phase C: Yt (into dead Slots region), then b-pairs: recompute P, combine ----
  transpose_bf16_kernel<u16><<<dim3(cD / 64, cES / 64, cB), 256, 0, stream>>>(
      Yv, Yt, cES, cD, (long)cES * cD, (long)cD * cES);
  for (int bp = 0; bp < 2; bp++) {
    const u16* Xb = Xbf + (long)(bp * 2) * cN * cD;
    // P2[z][n][es] = exp(X_{bp*2+z} . Phi^T), z=0,1
    gemm_nt<0><<<dim3(cES / 128, cN / 128, 2), 256, 0, stream>>>(
        Xb, Phibf, P2, cN, cES, cD, cD, cD, cES,
        (long)cN * cD, 0L, 1, (long)cN * cES, Z1, 0, 1);
    // out[z][n][d] = (P2[z] . Yt_{bp*2+z}^T) / Z2   (fp32)
    gemm_nt<4><<<dim3(cD / 128, cN / 128, 2), 256, 0, stream>>>(
        P2, Yt + (long)(bp * 2) * cD * cES, out_f + (long)(bp * 2) * cN * cD,
        cN, cD, cES, cES, cES, cD,
        (long)cN * cES, (long)cD * cES, 2, (long)cN * cD,
        Z2 + (long)(bp * 2) * cN, cN, 2);
  }
}

// Round 3
// 1168.589 us; speedup vs baseline: 1.1860x; 1.0644x over previous
//
#include <hip/hip_runtime.h>
#include <hip/hip_bf16.h>

using u16 = unsigned short;
using short8 = __attribute__((ext_vector_type(8))) short;
using floatx4 = __attribute__((ext_vector_type(4))) float;

#define DEVI static __device__ __forceinline__

constexpr int cB = 4, cN = 4096, cD = 768, cE = 4, cS = 1024, cH = 3072;
constexpr int cES = cE * cS; // 4096
constexpr int cHC = cH / 2;  // 1536 H-chunk

DEVI u16 f2bf(float f) {
  union { float f; unsigned u; } v; v.f = f;
  unsigned r = v.u + 0x7fffu + ((v.u >> 16) & 1u); // RNE
  return (u16)(r >> 16);
}
DEVI float bf2f(u16 b) {
  union { unsigned u; float f; } v; v.u = ((unsigned)b) << 16;
  return v.f;
}
DEVI float gelu_tanh(float x) {
  float z = 1.5957691216057308f * (x + 0.044715f * x * x * x);
  z = fminf(fmaxf(z, -30.f), 30.f);
  float e = __expf(z);
  float t = (e - 1.f) / (e + 1.f);
  return 0.5f * x * (1.f + t);
}

// async global->LDS, 16B per lane; lds dest = wave-uniform base + lane*16
DEVI void glds16(const u16* g, u16* l) {
  __builtin_amdgcn_global_load_lds(
      (const __attribute__((address_space(1))) void*)g,
      (__attribute__((address_space(3))) void*)l, 16, 0, 0);
}

// ---------------- zero fp32 buffer ----------------
__global__ __launch_bounds__(256) void zero_kernel(float* __restrict__ p, int n) {
  int i = blockIdx.x * 256 + threadIdx.x;
  if (i < n) p[i] = 0.f;
}

// ---------------- elementwise convert f32 -> bf16 ----------------
__global__ __launch_bounds__(256) void convert_kernel(const float* __restrict__ in,
                                                      u16* __restrict__ out, long n) {
  long stride = (long)gridDim.x * 256 * 4;
  for (long idx = ((long)blockIdx.x * 256 + threadIdx.x) * 4; idx < n; idx += stride) {
    float4 v = *(const float4*)(in + idx);
    ushort4 o;
    o.x = f2bf(v.x); o.y = f2bf(v.y); o.z = f2bf(v.z); o.w = f2bf(v.w);
    *(ushort4*)(out + idx) = o;
  }
}

// ---------------- batched transpose [R][C] -> [C][R], output bf16 ----------------
DEVI u16 to_bf(float f) { return f2bf(f); }
DEVI u16 to_bf(u16 u) { return u; }

template <typename Tin>
__global__ __launch_bounds__(256) void transpose_bf16_kernel(const Tin* __restrict__ in,
                                                             u16* __restrict__ out,
                                                             int R, int C,
                                                             long strideIn, long strideOut) {
  __shared__ u16 tile[64][65];
  const Tin* inb = in + (long)blockIdx.z * strideIn;
  u16* outb = out + (long)blockIdx.z * strideOut;
  const int r0 = blockIdx.y * 64, c0 = blockIdx.x * 64;
  const int tid = threadIdx.x;
#pragma unroll
  for (int i = 0; i < 16; i++) {
    int idx = i * 256 + tid;
    int r = idx >> 6, c = idx & 63;
    tile[r][c] = to_bf(inb[(long)(r0 + r) * C + (c0 + c)]);
  }
  __syncthreads();
#pragma unroll
  for (int i = 0; i < 16; i++) {
    int idx = i * 256 + tid;
    int r = idx >> 6, c = idx & 63;
    outb[(long)(c0 + r) * R + (r0 + c)] = tile[c][r];
  }
}

// ---------------- Z2: row sums (one block per row) ----------------
__global__ __launch_bounds__(256) void rowsum_kernel(const u16* __restrict__ P,
                                                     float* __restrict__ Z, int cols) {
  long base = (long)blockIdx.x * cols;
  int tid = threadIdx.x;
  float s = 0.f;
  for (int c = tid * 4; c < cols; c += 256 * 4) {
    ushort4 v = *(const ushort4*)(P + base + c);
    s += bf2f(v.x) + bf2f(v.y) + bf2f(v.z) + bf2f(v.w);
  }
  for (int o = 32; o > 0; o >>= 1) s += __shfl_down(s, o, 64);
  __shared__ float ws4[4];
  if ((tid & 63) == 0) ws4[tid >> 6] = s;
  __syncthreads();
  if (tid == 0) Z[blockIdx.x] = ws4[0] + ws4[1] + ws4[2] + ws4[3];
}

// ---------------- Z1: column sums, chunked + atomic (Z pre-zeroed) ----------------
__global__ __launch_bounds__(256) void colsum_kernel(const u16* __restrict__ P,
                                                     float* __restrict__ Z, int cols) {
  int col = blockIdx.x * 256 + threadIdx.x;
  int r0 = blockIdx.y * 256;
  float s = 0.f;
  for (int r = r0; r < r0 + 256; r++) s += bf2f(P[(long)r * cols + col]);
  atomicAdd(Z + col, s);
}

// ================= 128^2 engine (R1, kept for skinny grids) =================
template <int EPI>
__global__ __launch_bounds__(256, 2) void gemm_nt(const u16* __restrict__ A,
                                                  const u16* __restrict__ Bm,
                                                  void* __restrict__ Cout,
                                                  int M, int Nn, int K,
                                                  long ldA, long ldB, long ldC,
                                                  long strideA, long strideB, int modB,
                                                  long strideC,
                                                  const float* __restrict__ epiVec,
                                                  long epiStride, int epiMod) {
  __shared__ u16 lds[4 * 8192]; // 4 bufs x (A 4096 + B 4096) = 64KB

  const int gx = gridDim.x;
  const int nwg = gx * gridDim.y;
  int flat = blockIdx.y * gx + blockIdx.x;
  if ((nwg & 7) == 0) flat = (flat & 7) * (nwg >> 3) + (flat >> 3);
  const int bxs = flat % gx, bys = flat / gx;

  const int bz = blockIdx.z;
  const u16* Ab = A + (long)bz * strideA;
  const u16* Bb = Bm + (long)(bz % modB) * strideB;
  const float* ev = epiVec + (long)(bz % epiMod) * epiStride;
  const int tileM = bys * 128, tileN = bxs * 128;
  const int tid = threadIdx.x;
  const int wave = tid >> 6, lane = tid & 63;
  const int quad = lane >> 4, l16 = lane & 15;
  const int wm = (wave >> 1) * 64, wn = (wave & 1) * 64;

  const int swzk = (((lane & 3) ^ ((lane >> 3) & 3)) << 3);
  const int r0 = wave * 32 + (lane >> 2);
  const u16* aG0 = Ab + (long)(tileM + r0) * ldA + swzk;
  const u16* aG1 = Ab + (long)(tileM + r0 + 16) * ldA + swzk;
  const u16* bG0 = Bb + (long)(tileN + r0) * ldB + swzk;
  const u16* bG1 = Bb + (long)(tileN + r0 + 16) * ldB + swzk;
  const int ldsW = wave * 1024;

  const int NT = K >> 5;

  auto STAGE = [&](int tt) {
    u16* l = &lds[(tt & 3) * 8192];
    const long ko = (long)tt << 5;
    glds16(aG0 + ko, l + ldsW);
    glds16(aG1 + ko, l + ldsW + 512);
    glds16(bG0 + ko, l + 4096 + ldsW);
    glds16(bG1 + ko, l + 4096 + ldsW + 512);
  };

  floatx4 acc[4][4] = {};
  const int sread = ((quad ^ ((l16 >> 1) & 3)) << 3);

  STAGE(0);
  if (NT > 1) STAGE(1);
  if (NT > 2) STAGE(2);

  for (int t = 0; t < NT; t++) {
    asm volatile("s_barrier" ::: "memory");
    if (t + 3 < NT) STAGE(t + 3);
    const int ahead = NT - 1 - t;
    if (ahead >= 3)      asm volatile("s_waitcnt vmcnt(12)" ::: "memory");
    else if (ahead == 2) asm volatile("s_waitcnt vmcnt(8)" ::: "memory");
    else if (ahead == 1) asm volatile("s_waitcnt vmcnt(4)" ::: "memory");
    else                 asm volatile("s_waitcnt vmcnt(0)" ::: "memory");
    asm volatile("s_barrier" ::: "memory");

    const u16* As = &lds[(t & 3) * 8192];
    const u16* Bs = As + 4096;
    short8 af[4], bq[4];
#pragma unroll
    for (int i = 0; i < 4; i++)
      af[i] = *(const short8*)&As[(wm + i * 16 + l16) * 32 + sread];
#pragma unroll
    for (int j = 0; j < 4; j++)
      bq[j] = *(const short8*)&Bs[(wn + j * 16 + l16) * 32 + sread];
    __builtin_amdgcn_s_setprio(1);
#pragma unroll
    for (int i = 0; i < 4; i++)
#pragma unroll
      for (int j = 0; j < 4; j++)
        acc[i][j] = __builtin_amdgcn_mfma_f32_16x16x32_bf16(af[i], bq[j], acc[i][j], 0, 0, 0);
    __builtin_amdgcn_s_setprio(0);
  }

  const long cBase = (long)bz * strideC;
#pragma unroll
  for (int i = 0; i < 4; i++) {
#pragma unroll
    for (int r = 0; r < 4; r++) {
      const int row = tileM + wm + i * 16 + quad * 4 + r;
      float rscale = 1.f;
      if (EPI == 1 || EPI == 4) rscale = 1.f / ev[row];
#pragma unroll
      for (int j = 0; j < 4; j++) {
        const int col = tileN + wn + j * 16 + l16;
        float v = acc[i][j][r];
        const long cIdx = cBase + (long)row * ldC + col;
        if (EPI == 0) v = __expf(v);
        if (EPI == 1 || EPI == 4) v *= rscale;
        if (EPI == 2) v = gelu_tanh(v + ev[col]);
        if (EPI == 3) v = v + ev[col];
        if (EPI == 5) v = v + bf2f(((u16*)Cout)[cIdx]);
        if (EPI == 4)
          ((float*)Cout)[cIdx] = v;
        else
          ((u16*)Cout)[cIdx] = f2bf(v);
      }
    }
  }
}

// ================= 256^2 8-phase engine (T2+T3+T4+T5) =================
// BM=BN=256, BK=64, 8 waves (2M x 4N), per-wave out 128x64.
// LDS [buf2][A|B][khalf2][256*32] = 128KB; each kh region is one glds-linear
// half-tile. Region recycle (per tile kt, buf c=kt&1, phases ks-major):
//   ph0: rd A m0-3 ks0 + B ks0   | stage T(kt+1).A.kh1 -> buf c^1 (dead @ kt-1.ph3)
//   ph1: rd A m4-7 ks0           | stage T(kt+2).B.kh0 -> buf c   (dead @ ph0)
//   ph2: rd A m0-3 ks1 + B ks1   | stage T(kt+2).A.kh0 -> buf c   (dead @ ph1)
//   ph3: rd A m4-7 ks1           | stage T(kt+2).B.kh1 -> buf c   (dead @ ph2)
//   end ph3: vmcnt(6) = T(kt+1) complete (its newest half issued at kt.ph0),
//            leaving T(kt+2)'s 3 staged halves (6 loads) in flight.
template <int EPI>
__global__ __launch_bounds__(512, 2) void gemm256(const u16* __restrict__ A,
                                                  const u16* __restrict__ Bm,
                                                  void* __restrict__ Cout,
                                                  int M, int Nn, int K,
                                                  long ldA, long ldB, long ldC,
                                                  long strideA, long strideB, int modB,
                                                  long strideC,
                                                  const float* __restrict__ epiVec,
                                                  long epiStride, int epiMod) {
  __shared__ u16 lds[2][2][2][8192]; // [buf][A=0/B=1][kh][256 rows * 32 k]

  // bijective XCD swizzle (m204 form; works for any nwg)
  const int gx = gridDim.x;
  const int nwg = gx * gridDim.y;
  int flat = blockIdx.y * gx + blockIdx.x;
  {
    const int q = nwg >> 3, r = nwg & 7, xc = flat & 7, o = flat >> 3;
    flat = (xc < r ? xc * (q + 1) : r * (q + 1) + (xc - r) * q) + o;
  }
  const int bxs = flat % gx, bys = flat / gx;

  const int bz = blockIdx.z;
  const u16* __restrict__ Ab = A + (long)bz * strideA;
  const u16* __restrict__ Bb = Bm + (long)(bz % modB) * strideB;
  const float* __restrict__ ev = epiVec + (long)(bz % epiMod) * epiStride;
  const int tileM = bys * 256, tileN = bxs * 256;
  const int tid = threadIdx.x;
  const int wave = tid >> 6, lane = tid & 63;
  const int quad = lane >> 4, l16 = lane & 15;
  const int wr = wave >> 2, wc = wave & 3;

  // staging: half (kh region) = 256 rows x 32 k; wave w rows [w*32,+32),
  // call c rows +c*16; lane l -> row w*32+c*16+(l>>2), phys octet l&3.
  // T2 swizzle: phys octet p holds logical octet p ^ ((row>>1)&3) -> global
  // source k pre-swizzled; ds_read applies same XOR. (0 conflicts in R1.)
  const int kswz = (((lane & 3) ^ ((lane >> 3) & 3)) << 3);
  const int srow = wave * 32 + (lane >> 2);
  const u16* gA = Ab + (long)(tileM + srow) * ldA + kswz;
  const u16* gB = Bb + (long)(tileN + srow) * ldB + kswz;

  const int rdsw = ((quad ^ ((l16 >> 1) & 3)) << 3);
  const int aOff = (wr * 128 + l16) * 32 + rdsw; // + m*512
  const int bOff = (wc * 64 + l16) * 32 + rdsw;  // + n*512

  const int NT = K >> 6; // K multiple of 64, NT even >= 4 for all call sites

#define STA256(buf, kh, tt) do {                                   \
    const u16* _g = gA + ((long)(tt) << 6) + ((kh) << 5);          \
    u16* _l = &lds[buf][0][kh][wave * 1024];                       \
    glds16(_g, _l); glds16(_g + 16 * ldA, _l + 512); } while (0)
#define STB256(buf, kh, tt) do {                                   \
    const u16* _g = gB + ((long)(tt) << 6) + ((kh) << 5);          \
    u16* _l = &lds[buf][1][kh][wave * 1024];                       \
    glds16(_g, _l); glds16(_g + 16 * ldB, _l + 512); } while (0)
#define BAR256 asm volatile("s_barrier" ::: "memory")
#define LGK0   asm volatile("s_waitcnt lgkmcnt(0)" ::: "memory")

  floatx4 acc[8][4] = {};
  short8 af[4], bq[4];

  // ---- prologue: T0 all 4 halves; T1.{B.kh0, A.kh0, B.kh1} (issue order = ledger)
  STA256(0, 0, 0); STB256(0, 0, 0); STA256(0, 1, 0); STB256(0, 1, 0);
  STB256(1, 0, 1); STA256(1, 0, 1); STB256(1, 1, 1);
  asm volatile("s_waitcnt vmcnt(6)" ::: "memory"); // T0's 8 loads landed
  BAR256;

#define TILE256(kt, buf) do {                                                      \
    const bool s1 = (kt) + 1 < NT, s2 = (kt) + 2 < NT;                             \
    /* ---- ph0: A m0-3 ks0 + B ks0 ---- */                                        \
    _Pragma("unroll") for (int i = 0; i < 4; i++)                                  \
      af[i] = *(const short8*)&lds[buf][0][0][aOff + i * 512];                     \
    _Pragma("unroll") for (int n = 0; n < 4; n++)                                  \
      bq[n] = *(const short8*)&lds[buf][1][0][bOff + n * 512];                     \
    if (s1) STA256((buf) ^ 1, 1, (kt) + 1);                                        \
    BAR256; LGK0;                                                                  \
    __builtin_amdgcn_s_setprio(1);                                                 \
    _Pragma("unroll") for (int i = 0; i < 4; i++)                                  \
      _Pragma("unroll") for (int n = 0; n < 4; n++)                                \
        acc[i][n] = __builtin_amdgcn_mfma_f32_16x16x32_bf16(af[i], bq[n], acc[i][n], 0, 0, 0); \
    __builtin_amdgcn_s_setprio(0);                                                 \
    BAR256;                                                                        \
    /* ---- ph1: A m4-7 ks0 (B reused) ---- */                                     \
    _Pragma("unroll") for (int i = 0; i < 4; i++)                                  \
      af[i] = *(const short8*)&lds[buf][0][0][aOff + (4 + i) * 512];               \
    if (s2) STB256(buf, 0, (kt) + 2);                                              \
    BAR256; LGK0;                                                                  \
    __builtin_amdgcn_s_setprio(1);                                                 \
    _Pragma("unroll") for (int i = 0; i < 4; i++)                                  \
      _Pragma("unroll") for (int n = 0; n < 4; n++)                                \
        acc[4 + i][n] = __builtin_amdgcn_mfma_f32_16x16x32_bf16(af[i], bq[n], acc[4 + i][n], 0, 0, 0); \
    __builtin_amdgcn_s_setprio(0);                                                 \
    BAR256;                                                                        \
    /* ---- ph2: A m0-3 ks1 + B ks1 ---- */                                        \
    _Pragma("unroll") for (int i = 0; i < 4; i++)                                  \
      af[i] = *(const short8*)&lds[buf][0][1][aOff + i * 512];                     \
    _Pragma("unroll") for (int n = 0; n < 4; n++)                                  \
      bq[n] = *(const short8*)&lds[buf][1][1][bOff + n * 512];                     \
    if (s2) STA256(buf, 0, (kt) + 2);                                              \
    BAR256; LGK0;                                                                  \
    __builtin_amdgcn_s_setprio(1);                                                 \
    _Pragma("unroll") for (int i = 0; i < 4; i++)                                  \
      _Pragma("unroll") for (int n = 0; n < 4; n++)                                \
        acc[i][n] = __builtin_amdgcn_mfma_f32_16x16x32_bf16(af[i], bq[n], acc[i][n], 0, 0, 0); \
    __builtin_amdgcn_s_setprio(0);                                                 \
    BAR256;                                                                        \
    /* ---- ph3: A m4-7 ks1 ---- */                                                \
    _Pragma("unroll") for (int i = 0; i < 4; i++)                                  \
      af[i] = *(const short8*)&lds[buf][0][1][aOff + (4 + i) * 512];               \
    if (s2) STB256(buf, 1, (kt) + 2);                                              \
    BAR256; LGK0;                                                                  \
    __builtin_amdgcn_s_setprio(1);                                                 \
    _Pragma("unroll") for (int i = 0; i < 4; i++)                                  \
      _Pragma("unroll") for (int n = 0; n < 4; n++)                                \
        acc[4 + i][n] = __builtin_amdgcn_mfma_f32_16x16x32_bf16(af[i], bq[n], acc[4 + i][n], 0, 0, 0); \
    __builtin_amdgcn_s_setprio(0);                                                 \
    if (s2)      asm volatile("s_waitcnt vmcnt(6)" ::: "memory");                  \
    else if (s1) asm volatile("s_waitcnt vmcnt(0)" ::: "memory");                  \
    BAR256;                                                                        \
  } while (0)

  for (int kt = 0; kt < NT; kt += 2) {
    TILE256(kt, 0);
    TILE256(kt + 1, 1);
  }
#undef TILE256
#undef STA256
#undef STB256
#undef BAR256
#undef LGK0

  // ---- epilogue: row = tileM + wr*128 + m*16 + quad*4 + r, col = tileN + wc*64 + n*16 + l16
  const long cBase = (long)bz * strideC;
#pragma unroll
  for (int m = 0; m < 8; m++) {
#pragma unroll
    for (int r = 0; r < 4; r++) {
      const int row = tileM + wr * 128 + m * 16 + quad * 4 + r;
      float rscale = 1.f;
      if (EPI == 1 || EPI == 4) rscale = 1.f / ev[row];
#pragma unroll
      for (int n = 0; n < 4; n++) {
        const int col = tileN + wc * 64 + n * 16 + l16;
        float v = acc[m][n][r];
        const long cIdx = cBase + (long)row * ldC + col;
        if (EPI == 0) v = __expf(v);
        if (EPI == 1 || EPI == 4) v *= rscale;
        if (EPI == 2) v = gelu_tanh(v + ev[col]);
        if (EPI == 3) v = v + ev[col];
        if (EPI == 5) v = v + bf2f(((u16*)Cout)[cIdx]);
        if (EPI == 4)
          ((float*)Cout)[cIdx] = v;
        else
          ((u16*)Cout)[cIdx] = f2bf(v);
      }
    }
  }
}

extern "C" void kernel_launch(void* const* d_in, const int* in_sizes, int n_in,
                              void* d_out, int out_size, void* d_ws, size_t ws_size,
                              hipStream_t stream) {
  const float* x   = (const float*)d_in[0]; // [B,N,D]
  const float* phi = (const float*)d_in[1]; // [E,S,D]
  const float* w1  = (const float*)d_in[2]; // [E,D,H]
  const float* b1  = (const float*)d_in[3]; // [E,H]
  const float* w2  = (const float*)d_in[4]; // [E,H,D]
  const float* b2  = (const float*)d_in[5]; // [E,D]
  (void)in_sizes; (void)n_in; (void)out_size; (void)ws_size;
  float* out_f = (float*)d_out;

  char* ws = (char*)d_ws;
  size_t off = 0;
  auto carve = [&](size_t bytes) -> char* {
    char* p = ws + off;
    off += (bytes + 255) & ~(size_t)255;
    return p;
  };

  // ---- workspace (~187 MB total) ----
  const size_t SZ_P = (size_t)cN * cES * 2; // 33.55 MB
  char* R1 = carve(2 * SZ_P);               // 67.1 MB multi-use region
  u16* Pb  = (u16*)R1;                      // phase A: P_b [N][ES]
  u16* Ptb = (u16*)(R1 + SZ_P);             // phase A: Pt_b [ES][N]
  u16* Hc  = (u16*)R1;                      // phase B: H chunk [16][S][1536] (50.3 MB)
  u16* P2  = (u16*)R1;                      // phase C: P pair [2][N][ES] (67.1 MB)
  u16* Xbf = (u16*)carve((size_t)cB * cN * cD * 2);   // persistent (phase A + C)
  char* R3 = carve((size_t)cB * cD * cN * 2);
  u16* Xt = (u16*)R3;                       // phase A: [B][D][N]
  u16* Yv = (u16*)R3;                       // phase B/C: [B][ES][D]
  char* R4 = carve((size_t)cB * cES * cD * 2);
  u16* Slots = (u16*)R4;                    // phase A/B: [B][ES][D]
  u16* Yt    = (u16*)R4;                    // phase C: [B][D][ES]
  u16* Phibf = (u16*)carve((size_t)cES * cD * 2);     // persistent (recompute)
  u16* W1t = (u16*)carve((size_t)cE * cH * cD * 2);   // [e][h][d]
  u16* W2t = (u16*)carve((size_t)cE * cD * cH * 2);   // [e][d][h]
  float* Z1 = (float*)carve((size_t)cB * cES * 4);
  float* Z2 = (float*)carve((size_t)cB * cN * 4);

  // ---- phase 0: casts / weight transposes ----
  convert_kernel<<<2048, 256, 0, stream>>>(x, Xbf, (long)cB * cN * cD);
  convert_kernel<<<1024, 256, 0, stream>>>(phi, Phibf, (long)cES * cD);
  transpose_bf16_kernel<float><<<dim3(cH / 64, cD / 64, cE), 256, 0, stream>>>(
      w1, W1t, cD, cH, (long)cD * cH, (long)cH * cD);
  transpose_bf16_kernel<float><<<dim3(cD / 64, cH / 64, cE), 256, 0, stream>>>(
      w2, W2t, cH, cD, (long)cH * cD, (long)cD * cH);
  transpose_bf16_kernel<float><<<dim3(cD / 64, cN / 64, cB), 256, 0, stream>>>(
      x, Xt, cN, cD, (long)cN * cD, (long)cD * cN);
  zero_kernel<<<(cB * cES) / 256, 256, 0, stream>>>(Z1, cB * cES);

  // ---- phase A: per batch, P_b -> Z1,Z2 -> Pt_b -> Slots_b ----
  for (int b = 0; b < cB; b++) {
    const u16* Xb = Xbf + (long)b * cN * cD;
    // P_b[n][es] = exp(X_b . Phi^T)  (256^2 engine, 16x16 grid)
    gemm256<0><<<dim3(cES / 256, cN / 256, 1), 512, 0, stream>>>(
        Xb, Phibf, Pb, cN, cES, cD, cD, cD, cES,
        0L, 0L, 1, 0L, Z1, 0, 1);
    colsum_kernel<<<dim3(cES / 256, cN / 256, 1), 256, 0, stream>>>(
        Pb, Z1 + (long)b * cES, cES);
    rowsum_kernel<<<cN, 256, 0, stream>>>(Pb, Z2 + (long)b * cN, cES);
    transpose_bf16_kernel<u16><<<dim3(cES / 64, cN / 64, 1), 256, 0, stream>>>(
        Pb, Ptb, cN, cES, 0L, 0L);
    // Slots_b[es][d] = (Pt_b . Xt_b^T) / Z1_b  (skinny N=768 -> 128^2 engine)
    gemm_nt<1><<<dim3(cD / 128, cES / 128, 1), 256, 0, stream>>>(
        Ptb, Xt + (long)b * cD * cN, Slots + (long)b * cES * cD,
        cES, cD, cN, cN, cN, cD,
        0L, 0L, 1, 0L, Z1 + (long)b * cES, 0, 1);
  }

  // ---- phase B: MLP in 2 H-chunks (bz = b*4+e), 256^2 engine ----
  for (int hc = 0; hc < 2; hc++) {
    const int h0 = hc * cHC;
    gemm256<2><<<dim3(cHC / 256, cS / 256, cB * cE), 512, 0, stream>>>(
        Slots, W1t + (long)h0 * cD, Hc, cS, cHC, cD, cD, cD, cHC,
        (long)cS * cD, (long)cH * cD, cE, (long)cS * cHC, b1 + h0, cH, cE);
    if (hc == 0)
      gemm256<3><<<dim3(cD / 256, cS / 256, cB * cE), 512, 0, stream>>>(
          Hc, W2t + h0, Yv, cS, cD, cHC, cHC, cH, cD,
          (long)cS * cHC, (long)cD * cH, cE, (long)cS * cD, b2, cD, cE);
    else
      gemm256<5><<<dim3(cD / 256, cS / 256, cB * cE), 512, 0, stream>>>(
          Hc, W2t + h0, Yv, cS, cD, cHC, cHC, cH, cD,
          (long)cS * cHC, (long)cD * cH, cE, (long)cS * cD, b2, cD, cE);
  }

  // ---- phase C: Yt (into dead Slots region), then b-pairs: recompute P, combine ----
  transpose_bf16_kernel<u16><<<dim3(cD / 64, cES / 64, cB), 256, 0, stream>>>(
      Yv, Yt, cES, cD, (long)cES * cD, (long)cD * cES);
  for (int bp = 0; bp < 2; bp++) {
    const u16* Xb = Xbf + (long)(bp * 2) * cN * cD;
    // P2[z][n][es] = exp(X_{bp*2+z} . Phi^T)  (256^2 engine)
    gemm256<0><<<dim3(cES / 256, cN / 256, 2), 512, 0, stream>>>(
        Xb, Phibf, P2, cN, cES, cD, cD, cD, cES,
        (long)cN * cD, 0L, 1, (long)cN * cES, Z1, 0, 1);
    // out[z][n][d] = (P2[z] . Yt^T) / Z2 (skinny N=768, fp32 out -> 128^2 engine)
    gemm_nt<4><<<dim3(cD / 128, cN / 128, 2), 256, 0, stream>>>(
        P2, Yt + (long)(bp * 2) * cD * cES, out_f + (long)(bp * 2) * cN * cD,
        cN, cD, cES, cES, cES, cD,
        (long)cN * cES, (long)cD * cES, 2, (long)cN * cD,
        Z2 + (long)(bp * 2) * cN, cN, 2);
  }
}

// Round 4
// 1096.315 us; speedup vs baseline: 1.2642x; 1.0659x over previous
//
#include <hip/hip_runtime.h>
#include <hip/hip_bf16.h>

using u16 = unsigned short;
using short8 = __attribute__((ext_vector_type(8))) short;
using floatx4 = __attribute__((ext_vector_type(4))) float;

#define DEVI static __device__ __forceinline__

constexpr int cB = 4, cN = 4096, cD = 768, cE = 4, cS = 1024, cH = 3072;
constexpr int cES = cE * cS; // 4096
constexpr int cHC = cH / 2;  // 1536 H-chunk

DEVI u16 f2bf(float f) {
  union { float f; unsigned u; } v; v.f = f;
  unsigned r = v.u + 0x7fffu + ((v.u >> 16) & 1u); // RNE
  return (u16)(r >> 16);
}
DEVI float bf2f(u16 b) {
  union { unsigned u; float f; } v; v.u = ((unsigned)b) << 16;
  return v.f;
}
DEVI float gelu_tanh(float x) {
  float z = 1.5957691216057308f * (x + 0.044715f * x * x * x);
  z = fminf(fmaxf(z, -30.f), 30.f);
  float e = __expf(z);
  float t = (e - 1.f) / (e + 1.f);
  return 0.5f * x * (1.f + t);
}

// async global->LDS, 16B per lane; lds dest = wave-uniform base + lane*16
DEVI void glds16(const u16* g, u16* l) {
  __builtin_amdgcn_global_load_lds(
      (const __attribute__((address_space(1))) void*)g,
      (__attribute__((address_space(3))) void*)l, 16, 0, 0);
}

// ---------------- zero fp32 buffer ----------------
__global__ __launch_bounds__(256) void zero_kernel(float* __restrict__ p, int n) {
  int i = blockIdx.x * 256 + threadIdx.x;
  if (i < n) p[i] = 0.f;
}

// ---------------- elementwise convert f32 -> bf16 ----------------
__global__ __launch_bounds__(256) void convert_kernel(const float* __restrict__ in,
                                                      u16* __restrict__ out, long n) {
  long stride = (long)gridDim.x * 256 * 4;
  for (long idx = ((long)blockIdx.x * 256 + threadIdx.x) * 4; idx < n; idx += stride) {
    float4 v = *(const float4*)(in + idx);
    ushort4 o;
    o.x = f2bf(v.x); o.y = f2bf(v.y); o.z = f2bf(v.z); o.w = f2bf(v.w);
    *(ushort4*)(out + idx) = o;
  }
}

// ---------------- batched transpose [R][C] -> [C][R], output bf16 ----------------
DEVI u16 to_bf(float f) { return f2bf(f); }
DEVI u16 to_bf(u16 u) { return u; }

template <typename Tin>
__global__ __launch_bounds__(256) void transpose_bf16_kernel(const Tin* __restrict__ in,
                                                             u16* __restrict__ out,
                                                             int R, int C,
                                                             long strideIn, long strideOut) {
  __shared__ u16 tile[64][65];
  const Tin* inb = in + (long)blockIdx.z * strideIn;
  u16* outb = out + (long)blockIdx.z * strideOut;
  const int r0 = blockIdx.y * 64, c0 = blockIdx.x * 64;
  const int tid = threadIdx.x;
#pragma unroll
  for (int i = 0; i < 16; i++) {
    int idx = i * 256 + tid;
    int r = idx >> 6, c = idx & 63;
    tile[r][c] = to_bf(inb[(long)(r0 + r) * C + (c0 + c)]);
  }
  __syncthreads();
#pragma unroll
  for (int i = 0; i < 16; i++) {
    int idx = i * 256 + tid;
    int r = idx >> 6, c = idx & 63;
    outb[(long)(c0 + r) * R + (r0 + c)] = tile[c][r];
  }
}

// ================= 128^2 engine (R1, kept for skinny grids) =================
template <int EPI>
__global__ __launch_bounds__(256, 2) void gemm_nt(const u16* __restrict__ A,
                                                  const u16* __restrict__ Bm,
                                                  void* __restrict__ Cout,
                                                  int M, int Nn, int K,
                                                  long ldA, long ldB, long ldC,
                                                  long strideA, long strideB, int modB,
                                                  long strideC,
                                                  const float* __restrict__ epiVec,
                                                  long epiStride, int epiMod) {
  __shared__ u16 lds[4 * 8192]; // 4 bufs x (A 4096 + B 4096) = 64KB

  const int gx = gridDim.x;
  const int nwg = gx * gridDim.y;
  int flat = blockIdx.y * gx + blockIdx.x;
  if ((nwg & 7) == 0) flat = (flat & 7) * (nwg >> 3) + (flat >> 3);
  const int bxs = flat % gx, bys = flat / gx;

  const int bz = blockIdx.z;
  const u16* Ab = A + (long)bz * strideA;
  const u16* Bb = Bm + (long)(bz % modB) * strideB;
  const float* ev = epiVec + (long)(bz % epiMod) * epiStride;
  const int tileM = bys * 128, tileN = bxs * 128;
  const int tid = threadIdx.x;
  const int wave = tid >> 6, lane = tid & 63;
  const int quad = lane >> 4, l16 = lane & 15;
  const int wm = (wave >> 1) * 64, wn = (wave & 1) * 64;

  const int swzk = (((lane & 3) ^ ((lane >> 3) & 3)) << 3);
  const int r0 = wave * 32 + (lane >> 2);
  const u16* aG0 = Ab + (long)(tileM + r0) * ldA + swzk;
  const u16* aG1 = Ab + (long)(tileM + r0 + 16) * ldA + swzk;
  const u16* bG0 = Bb + (long)(tileN + r0) * ldB + swzk;
  const u16* bG1 = Bb + (long)(tileN + r0 + 16) * ldB + swzk;
  const int ldsW = wave * 1024;

  const int NT = K >> 5;

  auto STAGE = [&](int tt) {
    u16* l = &lds[(tt & 3) * 8192];
    const long ko = (long)tt << 5;
    glds16(aG0 + ko, l + ldsW);
    glds16(aG1 + ko, l + ldsW + 512);
    glds16(bG0 + ko, l + 4096 + ldsW);
    glds16(bG1 + ko, l + 4096 + ldsW + 512);
  };

  floatx4 acc[4][4] = {};
  const int sread = ((quad ^ ((l16 >> 1) & 3)) << 3);

  STAGE(0);
  if (NT > 1) STAGE(1);
  if (NT > 2) STAGE(2);

  for (int t = 0; t < NT; t++) {
    asm volatile("s_barrier" ::: "memory");
    if (t + 3 < NT) STAGE(t + 3);
    const int ahead = NT - 1 - t;
    if (ahead >= 3)      asm volatile("s_waitcnt vmcnt(12)" ::: "memory");
    else if (ahead == 2) asm volatile("s_waitcnt vmcnt(8)" ::: "memory");
    else if (ahead == 1) asm volatile("s_waitcnt vmcnt(4)" ::: "memory");
    else                 asm volatile("s_waitcnt vmcnt(0)" ::: "memory");
    asm volatile("s_barrier" ::: "memory");

    const u16* As = &lds[(t & 3) * 8192];
    const u16* Bs = As + 4096;
    short8 af[4], bq[4];
#pragma unroll
    for (int i = 0; i < 4; i++)
      af[i] = *(const short8*)&As[(wm + i * 16 + l16) * 32 + sread];
#pragma unroll
    for (int j = 0; j < 4; j++)
      bq[j] = *(const short8*)&Bs[(wn + j * 16 + l16) * 32 + sread];
    __builtin_amdgcn_s_setprio(1);
#pragma unroll
    for (int i = 0; i < 4; i++)
#pragma unroll
      for (int j = 0; j < 4; j++)
        acc[i][j] = __builtin_amdgcn_mfma_f32_16x16x32_bf16(af[i], bq[j], acc[i][j], 0, 0, 0);
    __builtin_amdgcn_s_setprio(0);
  }

  const long cBase = (long)bz * strideC;
#pragma unroll
  for (int i = 0; i < 4; i++) {
#pragma unroll
    for (int r = 0; r < 4; r++) {
      const int row = tileM + wm + i * 16 + quad * 4 + r;
      float rscale = 1.f;
      if (EPI == 1 || EPI == 4) rscale = 1.f / ev[row];
#pragma unroll
      for (int j = 0; j < 4; j++) {
        const int col = tileN + wn + j * 16 + l16;
        float v = acc[i][j][r];
        const long cIdx = cBase + (long)row * ldC + col;
        if (EPI == 0) v = __expf(v);
        if (EPI == 1 || EPI == 4) v *= rscale;
        if (EPI == 2) v = gelu_tanh(v + ev[col]);
        if (EPI == 3) v = v + ev[col];
        if (EPI == 5) v = v + bf2f(((u16*)Cout)[cIdx]);
        if (EPI == 4)
          ((float*)Cout)[cIdx] = v;
        else
          ((u16*)Cout)[cIdx] = f2bf(v);
      }
    }
  }
}

// ================= 256^2 8-phase engine (R3-verified K-loop, untouched) ========
// EPI 6: exp->bf16 + fused col-sums (Zc += per-col) and row-sums (Zr += per-row).
template <int EPI>
__global__ __launch_bounds__(512, 2) void gemm256(const u16* __restrict__ A,
                                                  const u16* __restrict__ Bm,
                                                  void* __restrict__ Cout,
                                                  int M, int Nn, int K,
                                                  long ldA, long ldB, long ldC,
                                                  long strideA, long strideB, int modB,
                                                  long strideC,
                                                  const float* __restrict__ epiVec,
                                                  long epiStride, int epiMod,
                                                  float* __restrict__ Zc,
                                                  float* __restrict__ Zr) {
  __shared__ u16 lds[2][2][2][8192]; // [buf][A=0/B=1][kh][256 rows * 32 k]

  // bijective XCD swizzle (m204 form; works for any nwg)
  const int gx = gridDim.x;
  const int nwg = gx * gridDim.y;
  int flat = blockIdx.y * gx + blockIdx.x;
  {
    const int q = nwg >> 3, r = nwg & 7, xc = flat & 7, o = flat >> 3;
    flat = (xc < r ? xc * (q + 1) : r * (q + 1) + (xc - r) * q) + o;
  }
  const int bxs = flat % gx, bys = flat / gx;

  const int bz = blockIdx.z;
  const u16* __restrict__ Ab = A + (long)bz * strideA;
  const u16* __restrict__ Bb = Bm + (long)(bz % modB) * strideB;
  const float* __restrict__ ev = epiVec + (long)(bz % epiMod) * epiStride;
  const int tileM = bys * 256, tileN = bxs * 256;
  const int tid = threadIdx.x;
  const int wave = tid >> 6, lane = tid & 63;
  const int quad = lane >> 4, l16 = lane & 15;
  const int wr = wave >> 2, wc = wave & 3;

  const int kswz = (((lane & 3) ^ ((lane >> 3) & 3)) << 3);
  const int srow = wave * 32 + (lane >> 2);
  const u16* gA = Ab + (long)(tileM + srow) * ldA + kswz;
  const u16* gB = Bb + (long)(tileN + srow) * ldB + kswz;

  const int rdsw = ((quad ^ ((l16 >> 1) & 3)) << 3);
  const int aOff = (wr * 128 + l16) * 32 + rdsw; // + m*512
  const int bOff = (wc * 64 + l16) * 32 + rdsw;  // + n*512

  const int NT = K >> 6; // K multiple of 64, NT even >= 4 for all call sites

#define STA256(buf, kh, tt) do {                                   \
    const u16* _g = gA + ((long)(tt) << 6) + ((kh) << 5);          \
    u16* _l = &lds[buf][0][kh][wave * 1024];                       \
    glds16(_g, _l); glds16(_g + 16 * ldA, _l + 512); } while (0)
#define STB256(buf, kh, tt) do {                                   \
    const u16* _g = gB + ((long)(tt) << 6) + ((kh) << 5);          \
    u16* _l = &lds[buf][1][kh][wave * 1024];                       \
    glds16(_g, _l); glds16(_g + 16 * ldB, _l + 512); } while (0)
#define BAR256 asm volatile("s_barrier" ::: "memory")
#define LGK0   asm volatile("s_waitcnt lgkmcnt(0)" ::: "memory")

  floatx4 acc[8][4] = {};
  short8 af[4], bq[4];

  // ---- prologue: T0 all 4 halves; T1.{B.kh0, A.kh0, B.kh1}
  STA256(0, 0, 0); STB256(0, 0, 0); STA256(0, 1, 0); STB256(0, 1, 0);
  STB256(1, 0, 1); STA256(1, 0, 1); STB256(1, 1, 1);
  asm volatile("s_waitcnt vmcnt(6)" ::: "memory"); // T0's 8 loads landed
  BAR256;

#define TILE256(kt, buf) do {                                                      \
    const bool s1 = (kt) + 1 < NT, s2 = (kt) + 2 < NT;                             \
    /* ---- ph0: A m0-3 ks0 + B ks0 ---- */                                        \
    _Pragma("unroll") for (int i = 0; i < 4; i++)                                  \
      af[i] = *(const short8*)&lds[buf][0][0][aOff + i * 512];                     \
    _Pragma("unroll") for (int n = 0; n < 4; n++)                                  \
      bq[n] = *(const short8*)&lds[buf][1][0][bOff + n * 512];                     \
    if (s1) STA256((buf) ^ 1, 1, (kt) + 1);                                        \
    BAR256; LGK0;                                                                  \
    __builtin_amdgcn_s_setprio(1);                                                 \
    _Pragma("unroll") for (int i = 0; i < 4; i++)                                  \
      _Pragma("unroll") for (int n = 0; n < 4; n++)                                \
        acc[i][n] = __builtin_amdgcn_mfma_f32_16x16x32_bf16(af[i], bq[n], acc[i][n], 0, 0, 0); \
    __builtin_amdgcn_s_setprio(0);                                                 \
    BAR256;                                                                        \
    /* ---- ph1: A m4-7 ks0 (B reused) ---- */                                     \
    _Pragma("unroll") for (int i = 0; i < 4; i++)                                  \
      af[i] = *(const short8*)&lds[buf][0][0][aOff + (4 + i) * 512];               \
    if (s2) STB256(buf, 0, (kt) + 2);                                              \
    BAR256; LGK0;                                                                  \
    __builtin_amdgcn_s_setprio(1);                                                 \
    _Pragma("unroll") for (int i = 0; i < 4; i++)                                  \
      _Pragma("unroll") for (int n = 0; n < 4; n++)                                \
        acc[4 + i][n] = __builtin_amdgcn_mfma_f32_16x16x32_bf16(af[i], bq[n], acc[4 + i][n], 0, 0, 0); \
    __builtin_amdgcn_s_setprio(0);                                                 \
    BAR256;                                                                        \
    /* ---- ph2: A m0-3 ks1 + B ks1 ---- */                                        \
    _Pragma("unroll") for (int i = 0; i < 4; i++)                                  \
      af[i] = *(const short8*)&lds[buf][0][1][aOff + i * 512];                     \
    _Pragma("unroll") for (int n = 0; n < 4; n++)                                  \
      bq[n] = *(const short8*)&lds[buf][1][1][bOff + n * 512];                     \
    if (s2) STA256(buf, 0, (kt) + 2);                                              \
    BAR256; LGK0;                                                                  \
    __builtin_amdgcn_s_setprio(1);                                                 \
    _Pragma("unroll") for (int i = 0; i < 4; i++)                                  \
      _Pragma("unroll") for (int n = 0; n < 4; n++)                                \
        acc[i][n] = __builtin_amdgcn_mfma_f32_16x16x32_bf16(af[i], bq[n], acc[i][n], 0, 0, 0); \
    __builtin_amdgcn_s_setprio(0);                                                 \
    BAR256;                                                                        \
    /* ---- ph3: A m4-7 ks1 ---- */                                                \
    _Pragma("unroll") for (int i = 0; i < 4; i++)                                  \
      af[i] = *(const short8*)&lds[buf][0][1][aOff + (4 + i) * 512];               \
    if (s2) STB256(buf, 1, (kt) + 2);                                              \
    BAR256; LGK0;                                                                  \
    __builtin_amdgcn_s_setprio(1);                                                 \
    _Pragma("unroll") for (int i = 0; i < 4; i++)                                  \
      _Pragma("unroll") for (int n = 0; n < 4; n++)                                \
        acc[4 + i][n] = __builtin_amdgcn_mfma_f32_16x16x32_bf16(af[i], bq[n], acc[4 + i][n], 0, 0, 0); \
    __builtin_amdgcn_s_setprio(0);                                                 \
    if (s2)      asm volatile("s_waitcnt vmcnt(6)" ::: "memory");                  \
    else if (s1) asm volatile("s_waitcnt vmcnt(0)" ::: "memory");                  \
    BAR256;                                                                        \
  } while (0)

  for (int kt = 0; kt < NT; kt += 2) {
    TILE256(kt, 0);
    TILE256(kt + 1, 1);
  }
#undef TILE256
#undef STA256
#undef STB256
#undef BAR256
#undef LGK0

  const long cBase = (long)bz * strideC;
  if (EPI == 6) {
    // exp + store + fused row/col sums. Zc/Zr pre-zeroed; atomic accumulate.
    float csum[4] = {0.f, 0.f, 0.f, 0.f};
#pragma unroll
    for (int m = 0; m < 8; m++) {
#pragma unroll
      for (int r = 0; r < 4; r++) {
        const int row = tileM + wr * 128 + m * 16 + quad * 4 + r;
        float rs = 0.f;
#pragma unroll
        for (int n = 0; n < 4; n++) {
          const int col = tileN + wc * 64 + n * 16 + l16;
          float v = __expf(acc[m][n][r]);
          ((u16*)Cout)[cBase + (long)row * ldC + col] = f2bf(v);
          rs += v;
          csum[n] += v;
        }
        // reduce rs across l16 (lanes within same quad share this row)
        rs += __shfl_xor(rs, 1, 64);
        rs += __shfl_xor(rs, 2, 64);
        rs += __shfl_xor(rs, 4, 64);
        rs += __shfl_xor(rs, 8, 64);
        if (l16 == 0) atomicAdd(&Zr[row], rs);
      }
    }
    // reduce csum across quads (lane^16, lane^32 keep l16, vary quad = vary rows)
#pragma unroll
    for (int n = 0; n < 4; n++) {
      float c = csum[n];
      c += __shfl_xor(c, 16, 64);
      c += __shfl_xor(c, 32, 64);
      if (quad == 0) atomicAdd(&Zc[tileN + wc * 64 + n * 16 + l16], c);
    }
  } else {
#pragma unroll
    for (int m = 0; m < 8; m++) {
#pragma unroll
      for (int r = 0; r < 4; r++) {
        const int row = tileM + wr * 128 + m * 16 + quad * 4 + r;
        float rscale = 1.f;
        if (EPI == 1 || EPI == 4) rscale = 1.f / ev[row];
#pragma unroll
        for (int n = 0; n < 4; n++) {
          const int col = tileN + wc * 64 + n * 16 + l16;
          float v = acc[m][n][r];
          const long cIdx = cBase + (long)row * ldC + col;
          if (EPI == 0) v = __expf(v);
          if (EPI == 1 || EPI == 4) v *= rscale;
          if (EPI == 2) v = gelu_tanh(v + ev[col]);
          if (EPI == 3) v = v + ev[col];
          if (EPI == 5) v = v + bf2f(((u16*)Cout)[cIdx]);
          if (EPI == 4)
            ((float*)Cout)[cIdx] = v;
          else
            ((u16*)Cout)[cIdx] = f2bf(v);
        }
      }
    }
  }
}

extern "C" void kernel_launch(void* const* d_in, const int* in_sizes, int n_in,
                              void* d_out, int out_size, void* d_ws, size_t ws_size,
                              hipStream_t stream) {
  const float* x   = (const float*)d_in[0]; // [B,N,D]
  const float* phi = (const float*)d_in[1]; // [E,S,D]
  const float* w1  = (const float*)d_in[2]; // [E,D,H]
  const float* b1  = (const float*)d_in[3]; // [E,H]
  const float* w2  = (const float*)d_in[4]; // [E,H,D]
  const float* b2  = (const float*)d_in[5]; // [E,D]
  (void)in_sizes; (void)n_in; (void)out_size;
  float* out_f = (float*)d_out;

  char* ws = (char*)d_ws;
  size_t off = 0;
  auto carve = [&](size_t bytes) -> char* {
    char* p = ws + off;
    off += (bytes + 255) & ~(size_t)255;
    return p;
  };

  const size_t SZ_P  = (size_t)cN * cES * 2;            // 32 MiB (one P batch)
  const size_t SZ_HC = (size_t)cB * cE * cS * cHC * 2;  // 48 MiB (H chunk)

  // Mode A (cacheP): keep all 4 P batches -> phase C skips the exp-GEMM recompute.
  // Needs ~304.3 MB; fall back to the R3 region-recycled layout otherwise.
  const bool cacheP = ws_size >= (size_t)306 * 1024 * 1024;

  u16 *Pall = nullptr, *PtA = nullptr, *HcA = nullptr;          // mode A
  u16 *Pb = nullptr, *Ptb = nullptr, *HcB = nullptr, *P2 = nullptr; // mode B
  if (cacheP) {
    Pall = (u16*)carve(4 * SZ_P);        // persistent through phase C
    char* RPH = carve(SZ_HC);            // Pt (phase A) then Hc (phase B)
    PtA = (u16*)RPH; HcA = (u16*)RPH;
  } else {
    char* R1 = carve(2 * SZ_P);          // multi-use region (R3 layout)
    Pb = (u16*)R1; Ptb = (u16*)(R1 + SZ_P); HcB = (u16*)R1; P2 = (u16*)R1;
  }
  u16* Xbf = (u16*)carve((size_t)cB * cN * cD * 2);
  char* R3r = carve((size_t)cB * cD * cN * 2);
  u16* Xt = (u16*)R3r;                   // phase A: [B][D][N]
  u16* Yv = (u16*)R3r;                   // phase B/C: [B][ES][D]
  char* R4r = carve((size_t)cB * cES * cD * 2);
  u16* Slots = (u16*)R4r;                // phase A/B
  u16* Yt    = (u16*)R4r;                // phase C
  u16* Phibf = (u16*)carve((size_t)cES * cD * 2);
  u16* W1t = (u16*)carve((size_t)cE * cH * cD * 2);   // [e][h][d]
  u16* W2t = (u16*)carve((size_t)cE * cD * cH * 2);   // [e][d][h]
  float* Z1 = (float*)carve((size_t)(cB * cES + cB * cN) * 4); // Z1 || Z2 contiguous
  float* Z2 = Z1 + (size_t)cB * cES;

  // ---- phase 0: casts / weight transposes / zero sums ----
  convert_kernel<<<2048, 256, 0, stream>>>(x, Xbf, (long)cB * cN * cD);
  convert_kernel<<<1024, 256, 0, stream>>>(phi, Phibf, (long)cES * cD);
  transpose_bf16_kernel<float><<<dim3(cH / 64, cD / 64, cE), 256, 0, stream>>>(
      w1, W1t, cD, cH, (long)cD * cH, (long)cH * cD);
  transpose_bf16_kernel<float><<<dim3(cD / 64, cH / 64, cE), 256, 0, stream>>>(
      w2, W2t, cH, cD, (long)cH * cD, (long)cD * cH);
  transpose_bf16_kernel<float><<<dim3(cD / 64, cN / 64, cB), 256, 0, stream>>>(
      x, Xt, cN, cD, (long)cN * cD, (long)cD * cN);
  zero_kernel<<<(cB * (cES + cN)) / 256, 256, 0, stream>>>(Z1, cB * (cES + cN));

  // ---- phase A: per batch, P_b (exp + fused Z1/Z2 sums) -> Pt_b -> Slots_b ----
  for (int b = 0; b < cB; b++) {
    const u16* Xb = Xbf + (long)b * cN * cD;
    u16* Pdst = cacheP ? Pall + (size_t)b * cN * cES : Pb;
    u16* Ptmp = cacheP ? PtA : Ptb;
    gemm256<6><<<dim3(cES / 256, cN / 256, 1), 512, 0, stream>>>(
        Xb, Phibf, Pdst, cN, cES, cD, cD, cD, cES,
        0L, 0L, 1, 0L, Z1, 0, 1,
        Z1 + (long)b * cES, Z2 + (long)b * cN);
    transpose_bf16_kernel<u16><<<dim3(cES / 64, cN / 64, 1), 256, 0, stream>>>(
        Pdst, Ptmp, cN, cES, 0L, 0L);
    // Slots_b[es][d] = (Pt_b . Xt_b^T) / Z1_b  (skinny N=768 -> 128^2 engine)
    gemm_nt<1><<<dim3(cD / 128, cES / 128, 1), 256, 0, stream>>>(
        Ptmp, Xt + (long)b * cD * cN, Slots + (long)b * cES * cD,
        cES, cD, cN, cN, cN, cD,
        0L, 0L, 1, 0L, Z1 + (long)b * cES, 0, 1);
  }

  // ---- phase B: MLP in 2 H-chunks (bz = b*4+e), 256^2 engine ----
  u16* Hc = cacheP ? HcA : HcB;
  for (int hc = 0; hc < 2; hc++) {
    const int h0 = hc * cHC;
    gemm256<2><<<dim3(cHC / 256, cS / 256, cB * cE), 512, 0, stream>>>(
        Slots, W1t + (long)h0 * cD, Hc, cS, cHC, cD, cD, cD, cHC,
        (long)cS * cD, (long)cH * cD, cE, (long)cS * cHC, b1 + h0, cH, cE,
        nullptr, nullptr);
    if (hc == 0)
      gemm256<3><<<dim3(cD / 256, cS / 256, cB * cE), 512, 0, stream>>>(
          Hc, W2t + h0, Yv, cS, cD, cHC, cHC, cH, cD,
          (long)cS * cHC, (long)cD * cH, cE, (long)cS * cD, b2, cD, cE,
          nullptr, nullptr);
    else
      gemm256<5><<<dim3(cD / 256, cS / 256, cB * cE), 512, 0, stream>>>(
          Hc, W2t + h0, Yv, cS, cD, cHC, cHC, cH, cD,
          (long)cS * cHC, (long)cD * cH, cE, (long)cS * cD, b2, cD, cE,
          nullptr, nullptr);
  }

  // ---- phase C: Yt (into dead Slots region); combine (P recompute only if !cacheP) ----
  transpose_bf16_kernel<u16><<<dim3(cD / 64, cES / 64, cB), 256, 0, stream>>>(
      Yv, Yt, cES, cD, (long)cES * cD, (long)cD * cES);
  for (int bp = 0; bp < 2; bp++) {
    const u16* Psrc;
    if (cacheP) {
      Psrc = Pall + (size_t)(bp * 2) * cN * cES; // [2][N][ES], stride cN*cES
    } else {
      const u16* Xb = Xbf + (long)(bp * 2) * cN * cD;
      gemm256<0><<<dim3(cES / 256, cN / 256, 2), 512, 0, stream>>>(
          Xb, Phibf, P2, cN, cES, cD, cD, cD, cES,
          (long)cN * cD, 0L, 1, (long)cN * cES, Z1, 0, 1, nullptr, nullptr);
      Psrc = P2;
    }
    // out[z][n][d] = (Psrc[z] . Yt_{bp*2+z}^T) / Z2   (fp32, 128^2 engine)
    gemm_nt<4><<<dim3(cD / 128, cN / 128, 2), 256, 0, stream>>>(
        Psrc, Yt + (long)(bp * 2) * cD * cES, out_f + (long)(bp * 2) * cN * cD,
        cN, cD, cES, cES, cES, cD,
        (long)cN * cES, (long)cD * cES, 2, (long)cN * cD,
        Z2 + (long)(bp * 2) * cN, cN, 2);
  }
}